// Round 2
// baseline (396.239 us; speedup 1.0000x reference)
//
#include <hip/hip_runtime.h>

#define N_ENT 500000
#define N_REL 200
#define DIMS 128
#define BATCH 16384
#define MARGIN 1.0f
#define CHUNK 16          // rows per k_main workgroup
#define MAXCHUNKS 1280    // >= 199 + ceil(BATCH/CHUNK) = 1223
#define GRID_MAIN 1280

// ws layout (int32 element indexing):
// 0                 nchunks
// 1                 done counter
// 2                 float accumulator (as bits)
// [16, 16+MAXCHUNKS)     chunk table: (rel<<20)|(cnt<<15)|globalRowStart
// [4096, 4096+BATCH)     bucketed row ids, grouped by relation

// ---------------- bucketing: one WG, LDS histogram/prefix/scatter ----------
__global__ void __launch_bounds__(1024) k_bucket(const int* __restrict__ data,
                                                 int* __restrict__ wsi) {
    __shared__ int cnt[N_REL];
    __shared__ int off[N_REL + 1];
    __shared__ int cur[N_REL];
    __shared__ int chunkbase[N_REL];

    const int tid = threadIdx.x;
    if (tid < N_REL) cnt[tid] = 0;
    __syncthreads();

    for (int i = tid; i < BATCH; i += 1024)
        atomicAdd(&cnt[data[i * 5 + 2]], 1);
    __syncthreads();

    if (tid == 0) {
        int run = 0, crun = 0;
        for (int r = 0; r < N_REL; ++r) {
            off[r] = run;
            chunkbase[r] = crun;
            run += cnt[r];
            crun += (cnt[r] + CHUNK - 1) / CHUNK;
        }
        off[N_REL] = run;
        wsi[0] = crun;      // nchunks
        wsi[1] = 0;         // done counter
        reinterpret_cast<float*>(wsi)[2] = 0.0f;
    }
    __syncthreads();

    // build chunk table: thread r handles relation r
    if (tid < N_REL) {
        int c = cnt[tid];
        int base = chunkbase[tid];
        int start = off[tid];
        int k = 0;
        while (c > 0) {
            int take = c < CHUNK ? c : CHUNK;
            wsi[16 + base + k] = (tid << 20) | (take << 15) | (start + k * CHUNK);
            c -= take;
            ++k;
        }
        cur[tid] = off[tid];
    }
    __syncthreads();

    for (int i = tid; i < BATCH; i += 1024) {
        int r = data[i * 5 + 2];
        int p = atomicAdd(&cur[r], 1);
        wsi[4096 + p] = i;
    }
}

__device__ __forceinline__ void fma4(float4& a, float s, const float4& b) {
    a.x = fmaf(s, b.x, a.x);
    a.y = fmaf(s, b.y, a.y);
    a.z = fmaf(s, b.z, a.z);
    a.w = fmaf(s, b.w, a.w);
}

// ---------------- main: one chunk (<=16 rows, one relation) per WG ---------
__global__ void __launch_bounds__(256, 4) k_main(const int* __restrict__ data,
                                                 const float* __restrict__ ent,
                                                 const float* __restrict__ rel,
                                                 int* __restrict__ wsi,
                                                 float* __restrict__ out) {
    __shared__ float4 sh[4][8][32];  // kind (h,t,ch,ct) x row x float4
    __shared__ float parts[4][8];    // wave x row

    const int tid  = threadIdx.x;
    const int c    = tid & 31;   // column float4 index (cols 4c..4c+3)
    const int rg   = tid >> 5;   // row group (rows 16*rg .. 16*rg+15)
    const int wave = tid >> 6;
    const int lane = tid & 63;

    const int nchunks = wsi[0];
    const int* bucket = wsi + 4096;
    float wgacc = 0.0f;

    if (blockIdx.x < (unsigned)nchunks) {
        const int packed = wsi[16 + blockIdx.x];
        const int r      = packed >> 20;
        const int cnt    = (packed >> 15) & 31;
        const int start  = packed & 0x7fff;

        // Register-resident R tile: row rg*16+k, cols 4c..4c+3
        const float* Rg = rel + (size_t)r * (DIMS * DIMS);
        float4 Rr[16];
#pragma unroll
        for (int k = 0; k < 16; ++k)
            Rr[k] = *reinterpret_cast<const float4*>(
                Rg + (size_t)(rg * 16 + k) * DIMS + c * 4);

        for (int b0 = 0; b0 < cnt; b0 += 8) {
            const int nv = min(8, cnt - b0);

            // Stage h,t,ch,ct for up to 8 rows (coalesced 512B per vector)
            for (int idx = tid; idx < 1024; idx += 256) {
                int f4   = idx & 31;
                int vid  = idx >> 5;
                int g    = vid >> 2;
                int kind = vid & 3;
                int gg   = (g < nv) ? g : (nv - 1);
                int b    = bucket[start + b0 + gg];
                int col  = (kind == 0) ? 0 : (kind == 1) ? 1 : (kind == 2) ? 3 : 4;
                int e    = data[b * 5 + col];
                sh[kind][g][f4] =
                    *reinterpret_cast<const float4*>(ent + (size_t)e * DIMS + f4 * 4);
            }
            __syncthreads();

            for (int g = 0; g < 8; ++g) {
                float4 up = {0.f, 0.f, 0.f, 0.f};
                float4 un = {0.f, 0.f, 0.f, 0.f};
#pragma unroll
                for (int kk = 0; kk < 4; ++kk) {
                    float4 h4 = sh[0][g][rg * 4 + kk];  // broadcast reads
                    float4 g4 = sh[2][g][rg * 4 + kk];
                    fma4(up, h4.x, Rr[kk * 4 + 0]);
                    fma4(up, h4.y, Rr[kk * 4 + 1]);
                    fma4(up, h4.z, Rr[kk * 4 + 2]);
                    fma4(up, h4.w, Rr[kk * 4 + 3]);
                    fma4(un, g4.x, Rr[kk * 4 + 0]);
                    fma4(un, g4.y, Rr[kk * 4 + 1]);
                    fma4(un, g4.z, Rr[kk * 4 + 2]);
                    fma4(un, g4.w, Rr[kk * 4 + 3]);
                }
                float4 t4  = sh[1][g][c];
                float4 ct4 = sh[3][g][c];
                float s = up.x * t4.x + up.y * t4.y + up.z * t4.z + up.w * t4.w
                        - (un.x * ct4.x + un.y * ct4.y + un.z * ct4.z + un.w * ct4.w);
                s += __shfl_xor(s, 32, 64);
                s += __shfl_xor(s, 16, 64);
                s += __shfl_xor(s, 8, 64);
                s += __shfl_xor(s, 4, 64);
                s += __shfl_xor(s, 2, 64);
                s += __shfl_xor(s, 1, 64);
                if (lane == 0) parts[wave][g] = s;
            }
            __syncthreads();

            if (tid < 8) {
                float v = parts[0][tid] + parts[1][tid] + parts[2][tid]
                        + parts[3][tid] + MARGIN;
                v = (tid < nv && v > 0.0f) ? v : 0.0f;
                v += __shfl_xor(v, 4, 64);
                v += __shfl_xor(v, 2, 64);
                v += __shfl_xor(v, 1, 64);
                if (tid == 0) wgacc += v;
            }
            __syncthreads();
        }
    }

    // every WG participates in the completion protocol
    if (tid == 0) {
        float* accf = reinterpret_cast<float*>(wsi) + 2;
        atomicAdd(accf, wgacc);
        __threadfence();
        int old = atomicAdd(&wsi[1], 1);
        if (old == (int)gridDim.x - 1) {
            float total = atomicAdd(accf, 0.0f);  // atomic read after all adds
            out[0] = total * (1.0f / (float)BATCH);
        }
    }
}

extern "C" void kernel_launch(void* const* d_in, const int* in_sizes, int n_in,
                              void* d_out, int out_size, void* d_ws, size_t ws_size,
                              hipStream_t stream) {
    const int*   data = (const int*)d_in[0];     // (BATCH,5) int32
    const float* ent  = (const float*)d_in[1];   // (N_ENT,128) f32
    const float* rel  = (const float*)d_in[2];   // (N_REL,128,128) f32
    float* out = (float*)d_out;
    int*   wsi = (int*)d_ws;

    k_bucket<<<1, 1024, 0, stream>>>(data, wsi);
    k_main<<<GRID_MAIN, 256, 0, stream>>>(data, ent, rel, wsi, out);
}

// Round 3
// 341.542 us; speedup vs baseline: 1.1601x; 1.1601x over previous
//
#include <hip/hip_runtime.h>

#define N_ENT 500000
#define N_REL 200
#define DIMS 128
#define BATCH 16384
#define MARGIN 1.0f
#define CHUNK 16
#define GRID_MAIN 1280

// ws int32 layout:
// [0]                  nchunks
// [16, 16+1300)        chunk table: (rel<<20)|(cnt<<15)|globalRowStart
// [4096, 4096+BATCH)   bucketed row ids, grouped by relation
// [8192, 8192+128)     float accumulator slots

// ---------------- bucketing: one WG, LDS histogram + parallel scan ---------
__global__ void __launch_bounds__(1024) k_bucket(const int* __restrict__ data,
                                                 int* __restrict__ wsi) {
    __shared__ int cnt[256];
    __shared__ int s1[256];   // inclusive scan of counts
    __shared__ int s2[256];   // inclusive scan of chunk counts
    __shared__ int cur[256];  // scatter cursors

    const int tid = threadIdx.x;
    if (tid < 256) cnt[tid] = 0;
    __syncthreads();

    for (int i = tid; i < BATCH; i += 1024)
        atomicAdd(&cnt[data[i * 5 + 2]], 1);
    __syncthreads();

    if (tid < 256) {
        s1[tid] = cnt[tid];
        s2[tid] = (cnt[tid] + CHUNK - 1) / CHUNK;
    }
    __syncthreads();

    // Hillis-Steele inclusive scan over 256 entries (all threads hit barriers)
    for (int d = 1; d < 256; d <<= 1) {
        int a = 0, b = 0;
        if (tid < 256 && tid >= d) { a = s1[tid - d]; b = s2[tid - d]; }
        __syncthreads();
        if (tid < 256 && tid >= d) { s1[tid] += a; s2[tid] += b; }
        __syncthreads();
    }

    if (tid < N_REL) {
        int c     = cnt[tid];
        int start = s1[tid] - c;
        int base  = s2[tid] - ((c + CHUNK - 1) / CHUNK);
        int k = 0;
        while (c > 0) {
            int take = c < CHUNK ? c : CHUNK;
            wsi[16 + base + k] = (tid << 20) | (take << 15) | (start + k * CHUNK);
            c -= take;
            ++k;
        }
    }
    if (tid < 256) cur[tid] = s1[tid] - cnt[tid];
    if (tid == 0) wsi[0] = s2[255];                     // nchunks
    if (tid < 128) reinterpret_cast<float*>(wsi)[8192 + tid] = 0.0f;
    __syncthreads();

    for (int i = tid; i < BATCH; i += 1024) {
        int r = data[i * 5 + 2];
        int p = atomicAdd(&cur[r], 1);
        wsi[4096 + p] = i;
    }
}

__device__ __forceinline__ void fma4(float4& a, float s, const float4& b) {
    a.x = fmaf(s, b.x, a.x);
    a.y = fmaf(s, b.y, a.y);
    a.z = fmaf(s, b.z, a.z);
    a.w = fmaf(s, b.w, a.w);
}
__device__ __forceinline__ float dot4(const float4& x, const float4& y) {
    return x.x * y.x + x.y * y.y + x.z * y.z + x.w * y.w;
}

// ---------------- main: one chunk (<=16 rows, one relation) per WG ---------
// Lane (a,b): a=tid>>4 owns R rows 8a..8a+7, b=tid&15 owns cols 8b..8b+7.
// 64 R elements register-resident per lane (16 float4).
__global__ void __launch_bounds__(256) k_main(const int* __restrict__ data,
                                              const float* __restrict__ ent,
                                              const float* __restrict__ rel,
                                              int* __restrict__ wsi) {
    __shared__ float4 sh[16][4][32];  // row g, kind (h,t,ch,ct), float4 idx
    __shared__ float parts[4][16];    // wave x row

    const int tid  = threadIdx.x;
    const int a    = tid >> 4;
    const int b    = tid & 15;
    const int wave = tid >> 6;
    const int lane = tid & 63;

    const int nchunks = wsi[0];
    if (blockIdx.x >= (unsigned)nchunks) return;  // uniform, before barriers

    const int packed = wsi[16 + blockIdx.x];
    const int r      = packed >> 20;
    const int cnt    = (packed >> 15) & 31;
    const int start  = packed & 0x7fff;

    // Register-resident R tile: rows 8a+k, cols 8b..8b+7
    const float* Rg = rel + (size_t)r * (DIMS * DIMS);
    float4 Rr[16];
#pragma unroll
    for (int k = 0; k < 8; ++k) {
        const float* rp = Rg + (size_t)(8 * a + k) * DIMS + 8 * b;
        Rr[2 * k]     = *reinterpret_cast<const float4*>(rp);
        Rr[2 * k + 1] = *reinterpret_cast<const float4*>(rp + 4);
    }

    // Stage all rows: 2048 float4, 8 iters, coalesced 512B per 32-lane group
    const int* bucket = wsi + 4096;
#pragma unroll
    for (int it = 0; it < 8; ++it) {
        int idx  = tid + it * 256;
        int f4   = idx & 31;
        int vid  = idx >> 5;
        int kind = vid & 3;
        int g    = vid >> 2;
        int gg   = (g < cnt) ? g : (cnt - 1);
        int bb   = bucket[start + gg];
        int col  = (kind == 0) ? 0 : (kind == 1) ? 1 : (kind == 2) ? 3 : 4;
        int e    = data[bb * 5 + col];
        sh[g][kind][f4] =
            *reinterpret_cast<const float4*>(ent + (size_t)e * DIMS + f4 * 4);
    }
    __syncthreads();

    for (int g = 0; g < 16; ++g) {
        const float4* hp = &sh[g][0][0];
        const float4* tp = &sh[g][1][0];
        const float4* cp = &sh[g][2][0];
        const float4* dp = &sh[g][3][0];
        float4 h0 = hp[2 * a], h1 = hp[2 * a + 1];   // rows 8a..8a+7 of h
        float4 c0 = cp[2 * a], c1 = cp[2 * a + 1];   // rows of ch
        float4 up0 = {0.f, 0.f, 0.f, 0.f}, up1 = up0, un0 = up0, un1 = up0;
        fma4(up0, h0.x, Rr[0]);  fma4(up1, h0.x, Rr[1]);
        fma4(up0, h0.y, Rr[2]);  fma4(up1, h0.y, Rr[3]);
        fma4(up0, h0.z, Rr[4]);  fma4(up1, h0.z, Rr[5]);
        fma4(up0, h0.w, Rr[6]);  fma4(up1, h0.w, Rr[7]);
        fma4(up0, h1.x, Rr[8]);  fma4(up1, h1.x, Rr[9]);
        fma4(up0, h1.y, Rr[10]); fma4(up1, h1.y, Rr[11]);
        fma4(up0, h1.z, Rr[12]); fma4(up1, h1.z, Rr[13]);
        fma4(up0, h1.w, Rr[14]); fma4(up1, h1.w, Rr[15]);
        fma4(un0, c0.x, Rr[0]);  fma4(un1, c0.x, Rr[1]);
        fma4(un0, c0.y, Rr[2]);  fma4(un1, c0.y, Rr[3]);
        fma4(un0, c0.z, Rr[4]);  fma4(un1, c0.z, Rr[5]);
        fma4(un0, c0.w, Rr[6]);  fma4(un1, c0.w, Rr[7]);
        fma4(un0, c1.x, Rr[8]);  fma4(un1, c1.x, Rr[9]);
        fma4(un0, c1.y, Rr[10]); fma4(un1, c1.y, Rr[11]);
        fma4(un0, c1.z, Rr[12]); fma4(un1, c1.z, Rr[13]);
        fma4(un0, c1.w, Rr[14]); fma4(un1, c1.w, Rr[15]);
        float4 t0 = tp[2 * b], t1 = tp[2 * b + 1];   // cols 8b..8b+7 of t
        float4 d0 = dp[2 * b], d1 = dp[2 * b + 1];
        float s = dot4(up0, t0) + dot4(up1, t1) - dot4(un0, d0) - dot4(un1, d1);
        s += __shfl_xor(s, 32, 64);
        s += __shfl_xor(s, 16, 64);
        s += __shfl_xor(s, 8, 64);
        s += __shfl_xor(s, 4, 64);
        s += __shfl_xor(s, 2, 64);
        s += __shfl_xor(s, 1, 64);
        if (lane == 0) parts[wave][g] = s;
    }
    __syncthreads();

    if (tid < 16) {
        float v = parts[0][tid] + parts[1][tid] + parts[2][tid] + parts[3][tid]
                + MARGIN;
        v = (tid < cnt && v > 0.0f) ? v : 0.0f;
        v += __shfl_xor(v, 8, 64);
        v += __shfl_xor(v, 4, 64);
        v += __shfl_xor(v, 2, 64);
        v += __shfl_xor(v, 1, 64);
        if (tid == 0)
            atomicAdd(reinterpret_cast<float*>(wsi) + 8192 + (blockIdx.x & 127), v);
    }
}

__global__ void k_final(const int* __restrict__ wsi, float* __restrict__ out) {
    const float* acc = reinterpret_cast<const float*>(wsi) + 8192;
    int t = threadIdx.x;
    float v = acc[t] + acc[t + 64];
    v += __shfl_xor(v, 32, 64);
    v += __shfl_xor(v, 16, 64);
    v += __shfl_xor(v, 8, 64);
    v += __shfl_xor(v, 4, 64);
    v += __shfl_xor(v, 2, 64);
    v += __shfl_xor(v, 1, 64);
    if (t == 0) out[0] = v * (1.0f / (float)BATCH);
}

extern "C" void kernel_launch(void* const* d_in, const int* in_sizes, int n_in,
                              void* d_out, int out_size, void* d_ws, size_t ws_size,
                              hipStream_t stream) {
    const int*   data = (const int*)d_in[0];     // (BATCH,5) int32
    const float* ent  = (const float*)d_in[1];   // (N_ENT,128) f32
    const float* rel  = (const float*)d_in[2];   // (N_REL,128,128) f32
    float* out = (float*)d_out;
    int*   wsi = (int*)d_ws;

    k_bucket<<<1, 1024, 0, stream>>>(data, wsi);
    k_main<<<GRID_MAIN, 256, 0, stream>>>(data, ent, rel, wsi);
    k_final<<<1, 64, 0, stream>>>(wsi, out);
}